// Round 1
// baseline (1147.164 us; speedup 1.0000x reference)
//
#include <hip/hip_runtime.h>
#include <hip/hip_bf16.h>

// AltAttention: x[2,2048,1024] -> qkv proj -> ALiBi attention (+key padding mask)
//   -> out proj. fp32 I/O. Threshold 1.18e-2 => bf16-grade ok on attention path.
// Design:
//   K1: split-bf16 (hi+lo) MFMA GEMM  qkv = x @ qkv_w^T, scatter q*0.125,k,v as bf16 [B,H,N,64]
//   K2: flash attention, bf16 MFMA QK^T / PV, fp32 online softmax, -1e30 masking
//   K3: split-bf16 MFMA GEMM  out = attn_out @ proj_w^T + proj_b
// MFMA 16x16x32 bf16 layouts (HW-verified per guide):
//   A: lane holds A[m=lane&15][k=(lane>>4)*8 + j], j=0..7 (contig 8 bf16)
//   B: lane holds B[k=(lane>>4)*8 + j][n=lane&15]
//   C/D: reg r -> row=(lane>>4)*4+r, col=lane&15

typedef short bf16x8 __attribute__((ext_vector_type(8)));
typedef float f32x4 __attribute__((ext_vector_type(4)));

#define NB 2
#define NSEQ 2048
#define NC 1024
#define NH 16
#define NHD 64

__device__ __forceinline__ unsigned short f2bf(float f) {
    unsigned int u = __float_as_uint(f);
    u += 0x7fffu + ((u >> 16) & 1u);   // RNE
    return (unsigned short)(u >> 16);
}
__device__ __forceinline__ float bf2f(unsigned short h) {
    return __uint_as_float(((unsigned int)h) << 16);
}

__device__ __forceinline__ void cvt_store(const float4 v, unsigned short* dh, unsigned short* dl) {
    unsigned short h0 = f2bf(v.x), h1 = f2bf(v.y), h2 = f2bf(v.z), h3 = f2bf(v.w);
    unsigned short l0 = f2bf(v.x - bf2f(h0)), l1 = f2bf(v.y - bf2f(h1));
    unsigned short l2 = f2bf(v.z - bf2f(h2)), l3 = f2bf(v.w - bf2f(h3));
    uint2 hp, lp;
    hp.x = (unsigned)h0 | ((unsigned)h1 << 16); hp.y = (unsigned)h2 | ((unsigned)h3 << 16);
    lp.x = (unsigned)l0 | ((unsigned)l1 << 16); lp.y = (unsigned)l2 | ((unsigned)l3 << 16);
    *(uint2*)dh = hp;
    *(uint2*)dl = lp;
}

// ---------------- split-bf16 GEMM: C[M x Nout] = A[M x 1024] * Bm[Nout x 1024]^T ----------------
// EPI 0: scatter into q(scaled)/k/v bf16 [B,H,N,64];  EPI 1: out[m*1024+n] = c + bias[n]
template <int EPI>
__global__ __launch_bounds__(256) void gemm_split(
    const float* __restrict__ A, const float* __restrict__ Bm,
    unsigned short* __restrict__ qws, unsigned short* __restrict__ kws,
    unsigned short* __restrict__ vws,
    float* __restrict__ outp, const float* __restrict__ bias)
{
    __shared__ unsigned short Ah[64][40], Al[64][40], Bh[64][40], Bl[64][40]; // +8 pad
    const int t = threadIdx.x;
    const int wave = t >> 6, lane = t & 63;
    const int lrow = lane & 15, quad = lane >> 4;
    const int rowBase = blockIdx.y * 64;
    const int colBase = blockIdx.x * 64;

    f32x4 acc[4];
    #pragma unroll
    for (int i = 0; i < 4; i++) acc[i] = (f32x4){0.f, 0.f, 0.f, 0.f};

    for (int kt = 0; kt < 1024; kt += 32) {
        __syncthreads();  // prior iteration's frag reads done before restage
        #pragma unroll
        for (int i = 0; i < 2; i++) {
            int idx = t + i * 256;           // 0..511 float4 slots
            int row = idx >> 3;              // 64 rows, 8 float4 per row
            int col4 = (idx & 7) * 4;        // 0..28
            float4 av = *(const float4*)&A[(size_t)(rowBase + row) * 1024 + kt + col4];
            float4 bv = *(const float4*)&Bm[(size_t)(colBase + row) * 1024 + kt + col4];
            cvt_store(av, &Ah[row][col4], &Al[row][col4]);
            cvt_store(bv, &Bh[row][col4], &Bl[row][col4]);
        }
        __syncthreads();

        bf16x8 ah = *(const bf16x8*)&Ah[wave * 16 + lrow][quad * 8];
        bf16x8 al = *(const bf16x8*)&Al[wave * 16 + lrow][quad * 8];
        #pragma unroll
        for (int nt = 0; nt < 4; nt++) {
            bf16x8 bh = *(const bf16x8*)&Bh[nt * 16 + lrow][quad * 8];
            bf16x8 bl = *(const bf16x8*)&Bl[nt * 16 + lrow][quad * 8];
            acc[nt] = __builtin_amdgcn_mfma_f32_16x16x32_bf16(ah, bh, acc[nt], 0, 0, 0);
            acc[nt] = __builtin_amdgcn_mfma_f32_16x16x32_bf16(al, bh, acc[nt], 0, 0, 0);
            acc[nt] = __builtin_amdgcn_mfma_f32_16x16x32_bf16(ah, bl, acc[nt], 0, 0, 0);
        }
    }

    const int m0 = rowBase + wave * 16 + quad * 4;
    if (EPI == 0) {
        #pragma unroll
        for (int nt = 0; nt < 4; nt++) {
            int ncol = colBase + nt * 16 + lrow;        // 0..3071
            int three = ncol >> 10;
            int hh = (ncol >> 6) & 15;
            int d = ncol & 63;
            unsigned short* dst = (three == 0) ? qws : ((three == 1) ? kws : vws);
            float sc = (three == 0) ? 0.125f : 1.0f;    // SCALE=HD^-0.5, exact pow2
            #pragma unroll
            for (int r = 0; r < 4; r++) {
                int m = m0 + r;
                int bb = m >> 11, nn = m & 2047;
                dst[(((size_t)(bb * NH + hh)) * NSEQ + nn) * NHD + d] = f2bf(acc[nt][r] * sc);
            }
        }
    } else {
        #pragma unroll
        for (int nt = 0; nt < 4; nt++) {
            int ncol = colBase + nt * 16 + lrow;
            float bv = bias[ncol];
            #pragma unroll
            for (int r = 0; r < 4; r++) {
                outp[(size_t)(m0 + r) * 1024 + ncol] = acc[nt][r] + bv;
            }
        }
    }
}

// ---------------- fused flash attention ----------------
// grid: (N/64, B*H) x 256 threads. Each wave owns 16 q rows. 32-key tiles.
__global__ __launch_bounds__(256) void attn_fused(
    const unsigned short* __restrict__ qws, const unsigned short* __restrict__ kws,
    const unsigned short* __restrict__ vws,
    const float* __restrict__ alibi, const int* __restrict__ mask,
    float* __restrict__ attn_out)
{
    __shared__ unsigned short Klds[32][72];      // [key][d], +8 pad
    __shared__ unsigned short Vt[64][40];        // [d][key], +8 pad
    __shared__ unsigned short Plds[4][16][40];   // per-wave [qrow][key], +8 pad

    const int t = threadIdx.x;
    const int wave = t >> 6, lane = t & 63;
    const int lrow = lane & 15, quad = lane >> 4;
    const int bh = blockIdx.y;
    const int b = bh >> 4;
    const int q0 = blockIdx.x * 64;

    const size_t qkvbase = (size_t)bh * NSEQ * NHD;

    // Q fragments live in registers for the whole kernel (16B global loads)
    const int qrow = q0 + wave * 16 + lrow;
    bf16x8 qf0 = *(const bf16x8*)&qws[qkvbase + (size_t)qrow * NHD + quad * 8];
    bf16x8 qf1 = *(const bf16x8*)&qws[qkvbase + (size_t)qrow * NHD + 32 + quad * 8];

    float mrow[4], lsum[4];
    f32x4 acc[4];
    #pragma unroll
    for (int r = 0; r < 4; r++) { mrow[r] = -1e30f; lsum[r] = 0.f; }
    #pragma unroll
    for (int i = 0; i < 4; i++) acc[i] = (f32x4){0.f, 0.f, 0.f, 0.f};

    const float* alibi_b = alibi + ((size_t)bh * NSEQ + q0 + wave * 16) * NSEQ;
    const int* mask_b = mask + b * NSEQ;

    for (int kk0 = 0; kk0 < NSEQ; kk0 += 32) {
        // ---- stage K tile [32][64] and V^T tile [64][32] as bf16 ----
        {
            int key = t >> 3;
            int dcol = (t & 7) * 8;
            *(uint4*)&Klds[key][dcol] =
                *(const uint4*)&kws[qkvbase + (size_t)(kk0 + key) * NHD + dcol];
            unsigned short vv[8];
            *(uint4*)vv = *(const uint4*)&vws[qkvbase + (size_t)(kk0 + key) * NHD + dcol];
            #pragma unroll
            for (int i = 0; i < 8; i++) Vt[dcol + i][key] = vv[i];
        }
        __syncthreads();

        // ---- S = Q K^T (+scale already in q) : two 16x16 tiles over 32 keys ----
        f32x4 s0 = (f32x4){0.f, 0.f, 0.f, 0.f};
        f32x4 s1 = (f32x4){0.f, 0.f, 0.f, 0.f};
        {
            bf16x8 k0a = *(const bf16x8*)&Klds[lrow][quad * 8];
            bf16x8 k0b = *(const bf16x8*)&Klds[lrow][32 + quad * 8];
            s0 = __builtin_amdgcn_mfma_f32_16x16x32_bf16(qf0, k0a, s0, 0, 0, 0);
            s0 = __builtin_amdgcn_mfma_f32_16x16x32_bf16(qf1, k0b, s0, 0, 0, 0);
            bf16x8 k1a = *(const bf16x8*)&Klds[16 + lrow][quad * 8];
            bf16x8 k1b = *(const bf16x8*)&Klds[16 + lrow][32 + quad * 8];
            s1 = __builtin_amdgcn_mfma_f32_16x16x32_bf16(qf0, k1a, s1, 0, 0, 0);
            s1 = __builtin_amdgcn_mfma_f32_16x16x32_bf16(qf1, k1b, s1, 0, 0, 0);
        }

        // ---- alibi + mask + online softmax (rows quad*4+r, cols lrow within quad) ----
        const int key0 = kk0 + lrow, key1 = kk0 + 16 + lrow;
        const int msk0 = mask_b[key0], msk1 = mask_b[key1];
        #pragma unroll
        for (int r = 0; r < 4; r++) {
            size_t aoff = (size_t)(quad * 4 + r) * NSEQ;
            float v0 = msk0 ? -1e30f : (s0[r] + alibi_b[aoff + key0]);
            float v1 = msk1 ? -1e30f : (s1[r] + alibi_b[aoff + key1]);
            float mx = fmaxf(v0, v1);
            mx = fmaxf(mx, __shfl_xor(mx, 1, 64));
            mx = fmaxf(mx, __shfl_xor(mx, 2, 64));
            mx = fmaxf(mx, __shfl_xor(mx, 4, 64));
            mx = fmaxf(mx, __shfl_xor(mx, 8, 64));
            float mn = fmaxf(mrow[r], mx);
            float alpha = __expf(mrow[r] - mn);
            mrow[r] = mn;
            float p0 = __expf(v0 - mn);
            float p1 = __expf(v1 - mn);
            float ps = p0 + p1;
            ps += __shfl_xor(ps, 1, 64);
            ps += __shfl_xor(ps, 2, 64);
            ps += __shfl_xor(ps, 4, 64);
            ps += __shfl_xor(ps, 8, 64);
            lsum[r] = lsum[r] * alpha + ps;
            #pragma unroll
            for (int nt = 0; nt < 4; nt++) acc[nt][r] *= alpha;
            Plds[wave][quad * 4 + r][lrow] = f2bf(p0);
            Plds[wave][quad * 4 + r][16 + lrow] = f2bf(p1);
        }

        // ---- O += P V : P via LDS transpose into A-layout; V^T gives B-layout ----
        {
            bf16x8 pf = *(const bf16x8*)&Plds[wave][lrow][quad * 8];
            #pragma unroll
            for (int nt = 0; nt < 4; nt++) {
                bf16x8 vf = *(const bf16x8*)&Vt[nt * 16 + lrow][quad * 8];
                acc[nt] = __builtin_amdgcn_mfma_f32_16x16x32_bf16(pf, vf, acc[nt], 0, 0, 0);
            }
        }
        __syncthreads();
    }

    // ---- epilogue: normalize and write [B,N, h*64+d] fp32 ----
    const int h = bh & 15;
    #pragma unroll
    for (int nt = 0; nt < 4; nt++) {
        #pragma unroll
        for (int r = 0; r < 4; r++) {
            float inv = 1.f / lsum[r];
            attn_out[(size_t)(b * NSEQ + q0 + wave * 16 + quad * 4 + r) * NC
                     + h * 64 + nt * 16 + lrow] = acc[nt][r] * inv;
        }
    }
}

extern "C" void kernel_launch(void* const* d_in, const int* in_sizes, int n_in,
                              void* d_out, int out_size, void* d_ws, size_t ws_size,
                              hipStream_t stream) {
    const float* x      = (const float*)d_in[0];
    const int*   mask   = (const int*)d_in[1];     // bool -> int32 per harness
    const float* alibi  = (const float*)d_in[2];
    const float* qkv_w  = (const float*)d_in[3];
    const float* proj_w = (const float*)d_in[4];
    const float* proj_b = (const float*)d_in[5];
    float* out = (float*)d_out;

    char* w = (char*)d_ws;
    unsigned short* qws = (unsigned short*)(w);                     // 8 MB
    unsigned short* kws = (unsigned short*)(w + 8388608);           // 8 MB
    unsigned short* vws = (unsigned short*)(w + 16777216);          // 8 MB
    float* attn_out     = (float*)(w + 25165824);                   // 16 MB

    // K1: qkv projection (M=4096, N=3072, K=1024)
    gemm_split<0><<<dim3(48, 64), 256, 0, stream>>>(x, qkv_w, qws, kws, vws, nullptr, nullptr);
    // K2: attention
    attn_fused<<<dim3(32, 32), 256, 0, stream>>>(qws, kws, vws, alibi, mask, attn_out);
    // K3: output projection (M=4096, N=1024, K=1024) + bias
    gemm_split<1><<<dim3(16, 64), 256, 0, stream>>>(attn_out, proj_w, nullptr, nullptr, nullptr, out, proj_b);
}

// Round 2
// 947.839 us; speedup vs baseline: 1.2103x; 1.2103x over previous
//
#include <hip/hip_runtime.h>
#include <hip/hip_bf16.h>

// AltAttention: x[2,2048,1024] -> qkv proj -> ALiBi attention (+key padding mask) -> out proj.
// R2 design:
//   conv: x -> x2 [4096][2048] bf16 (hi,lo per elem);  qkv_w/proj_w -> (hi,hi) doubled-K
//   K1: plain bf16 MFMA GEMM K'=2048 (m97 structure: 128x128 tile, BK=64, global_load_lds x16)
//       epilogue scatters q*0.125 / k as [bh][n][64], v TRANSPOSED as vT[bh][d][2048]
//   K2: flash attention, 64q x 64key tiles, double-buffered global_load_lds K/V staging,
//       register-prefetched alibi+mask (1 tile ahead), fp32 online softmax, -1e30 masking,
//       epilogue writes attention out as (hi,lo) doubled-K bf16 [4096][2048]
//   K3: same GEMM (BN=64), bias epilogue -> fp32 out
// MFMA 16x16x32 bf16 layouts (HW-verified): A: lane m=lane&15, k=quad*8+j ;
//   B: k=quad*8+j, n=lane&15 ; C/D: row=quad*4+r, col=lane&15 (quad=lane>>4)

typedef short bf16x8 __attribute__((ext_vector_type(8)));
typedef float f32x4 __attribute__((ext_vector_type(4)));

#define NSEQ 2048
#define NH 16

__device__ __forceinline__ unsigned short f2bf(float f) {
    unsigned int u = __float_as_uint(f);
    u += 0x7fffu + ((u >> 16) & 1u);   // RNE
    return (unsigned short)(u >> 16);
}
__device__ __forceinline__ float bf2f(unsigned short h) {
    return __uint_as_float(((unsigned int)h) << 16);
}

__device__ __forceinline__ void gll16(const void* g, void* l) {
    __builtin_amdgcn_global_load_lds(
        (const __attribute__((address_space(1))) unsigned int*)g,
        (__attribute__((address_space(3))) unsigned int*)l, 16, 0, 0);
}

// ---------------- operand conversion: fp32 [R][1024] -> bf16 [R][2048] ----------------
// dup=0: (hi, lo) per element (A-side, fp32-accurate); dup=1: (hi, hi) (B-side)
__global__ __launch_bounds__(256) void conv2(const float* __restrict__ in,
                                             unsigned short* __restrict__ outp,
                                             int n4, int dup) {
    int i = blockIdx.x * 256 + threadIdx.x;
    if (i >= n4) return;
    float4 v = ((const float4*)in)[i];
    float vs[4] = {v.x, v.y, v.z, v.w};
    unsigned r[4];
    #pragma unroll
    for (int j = 0; j < 4; ++j) {
        unsigned short hh = f2bf(vs[j]);
        unsigned short ll = dup ? hh : f2bf(vs[j] - bf2f(hh));
        r[j] = (unsigned)hh | ((unsigned)ll << 16);
    }
    uint4 pk; pk.x = r[0]; pk.y = r[1]; pk.z = r[2]; pk.w = r[3];
    *(uint4*)&outp[(size_t)i * 8] = pk;
}

// ---------------- m97-style bf16 GEMM: C[4096 x Nout] = A2[4096 x 2048] . B2[Nout x 2048]^T --
// EPI 0 (BN=128): scatter q(*0.125)/k as [bh][n][64], v transposed as vT[bh][d][2048]
// EPI 1 (BN=64):  out[m][col] = c + bias[col] (fp32)
template <int EPI, int BN>
__global__ __launch_bounds__(256) void gemm2k(
    const unsigned short* __restrict__ A2, const unsigned short* __restrict__ B2,
    unsigned short* __restrict__ qo, unsigned short* __restrict__ ko,
    unsigned short* __restrict__ vto, float* __restrict__ outp,
    const float* __restrict__ bias)
{
    constexpr int K2 = 2048;
    constexpr int NT = BN / 32;   // 16-col frags per wave
    __shared__ __align__(16) unsigned short Ash[128 * 64];
    __shared__ __align__(16) unsigned short Bsh[BN * 64];
    const int t = threadIdx.x;
    const int wave = t >> 6, lane = t & 63;
    const int lrow = lane & 15, quad = lane >> 4;
    const int wr = wave & 1, wc = wave >> 1;
    const int rowBase = blockIdx.y * 128;
    const int colBase = blockIdx.x * BN;

    f32x4 acc[4][NT];
    #pragma unroll
    for (int mt = 0; mt < 4; ++mt)
        #pragma unroll
        for (int nt = 0; nt < NT; ++nt)
            acc[mt][nt] = (f32x4){0.f, 0.f, 0.f, 0.f};

    const int srow = lane >> 3;
    const int scol = (lane & 7) * 16;   // byte offset in 128-B tile row
    const char* Ag = (const char*)A2 + ((size_t)(rowBase + wave * 32 + srow) * K2) * 2 + scol;
    char* Als = (char*)Ash + (wave * 32 + srow) * 128 + scol;
    const char* Bg = (const char*)B2 + ((size_t)(colBase + wave * (BN / 4) + srow) * K2) * 2 + scol;
    char* Bls = (char*)Bsh + (wave * (BN / 4) + srow) * 128 + scol;

    for (int kt = 0; kt < K2; kt += 64) {
        __syncthreads();   // prior iteration's frag reads complete
        #pragma unroll
        for (int j = 0; j < 4; ++j)
            gll16(Ag + ((size_t)j * 8 * K2 + kt) * 2, Als + j * 8 * 128);
        #pragma unroll
        for (int j = 0; j < BN / 32; ++j)
            gll16(Bg + ((size_t)j * 8 * K2 + kt) * 2, Bls + j * 8 * 128);
        __syncthreads();   // drains vmcnt -> staging visible
        #pragma unroll
        for (int ks = 0; ks < 2; ++ks) {
            bf16x8 af[4], bfr[NT];
            #pragma unroll
            for (int mt = 0; mt < 4; ++mt)
                af[mt] = *(const bf16x8*)&Ash[(wr * 64 + mt * 16 + lrow) * 64 + ks * 32 + quad * 8];
            #pragma unroll
            for (int nt = 0; nt < NT; ++nt)
                bfr[nt] = *(const bf16x8*)&Bsh[(wc * (BN / 2) + nt * 16 + lrow) * 64 + ks * 32 + quad * 8];
            #pragma unroll
            for (int mt = 0; mt < 4; ++mt)
                #pragma unroll
                for (int nt = 0; nt < NT; ++nt)
                    acc[mt][nt] = __builtin_amdgcn_mfma_f32_16x16x32_bf16(af[mt], bfr[nt], acc[mt][nt], 0, 0, 0);
        }
    }

    #pragma unroll
    for (int mt = 0; mt < 4; ++mt) {
        const int m0 = rowBase + wr * 64 + mt * 16 + quad * 4;
        const int bb = m0 >> 11, nn0 = m0 & 2047;
        #pragma unroll
        for (int nt = 0; nt < NT; ++nt) {
            const int col = colBase + wc * (BN / 2) + nt * 16 + lrow;
            if (EPI == 0) {
                const int three = col >> 10;           // block-uniform (128 | 1024)
                const int hh2 = (col >> 6) & 15, dd = col & 63;
                const size_t bhh = (size_t)bb * NH + hh2;
                if (three == 0) {
                    #pragma unroll
                    for (int r = 0; r < 4; ++r)
                        qo[(bhh * NSEQ + nn0 + r) * 64 + dd] = f2bf(acc[mt][nt][r] * 0.125f);
                } else if (three == 1) {
                    #pragma unroll
                    for (int r = 0; r < 4; ++r)
                        ko[(bhh * NSEQ + nn0 + r) * 64 + dd] = f2bf(acc[mt][nt][r]);
                } else {
                    unsigned short pk[4];
                    #pragma unroll
                    for (int r = 0; r < 4; ++r) pk[r] = f2bf(acc[mt][nt][r]);
                    uint2 u; u.x = (unsigned)pk[0] | ((unsigned)pk[1] << 16);
                    u.y = (unsigned)pk[2] | ((unsigned)pk[3] << 16);
                    *(uint2*)&vto[(bhh * 64 + dd) * NSEQ + nn0] = u;   // nn0 % 4 == 0
                }
            } else {
                const float bv = bias[col];
                #pragma unroll
                for (int r = 0; r < 4; ++r)
                    outp[(size_t)(m0 + r) * 1024 + col] = acc[mt][nt][r] + bv;
            }
        }
    }
}

// ---------------- fused flash attention ----------------
// grid (32 q-tiles, 32 bh) x 256. Wave owns 16 q rows; 64-key tiles, 32 iters.
__global__ __launch_bounds__(256) void attn_fused(
    const unsigned short* __restrict__ qws, const unsigned short* __restrict__ kws,
    const unsigned short* __restrict__ vtws,
    const float* __restrict__ alibi, const int* __restrict__ mask,
    unsigned short* __restrict__ ao2)
{
    __shared__ __align__(16) unsigned short Klds[2][64][64];  // [buf][key][d]
    __shared__ __align__(16) unsigned short Vt[2][64][64];    // [buf][d][key]
    __shared__ __align__(16) unsigned short Plds[4][16][72];  // per-wave [q][key], padded

    const int t = threadIdx.x;
    const int wave = t >> 6, lane = t & 63;
    const int lrow = lane & 15, quad = lane >> 4;
    const int bh = blockIdx.y, b = bh >> 4, h = bh & 15;
    const int q0 = blockIdx.x * 64;
    const size_t kvbase = (size_t)bh * NSEQ * 64;   // elements

    const int qrow = q0 + wave * 16 + lrow;
    bf16x8 qf0 = *(const bf16x8*)&qws[kvbase + (size_t)qrow * 64 + quad * 8];
    bf16x8 qf1 = *(const bf16x8*)&qws[kvbase + (size_t)qrow * 64 + 32 + quad * 8];

    const float* alibi_w = alibi + ((size_t)bh * NSEQ + q0 + wave * 16 + quad * 4) * NSEQ;
    const int* mask_b = mask + b * NSEQ;

    const int srow = lane >> 3;
    const int scol = (lane & 7) * 16;  // bytes

    auto stage = [&](int kk0, int buf) {
        #pragma unroll
        for (int j = 0; j < 2; ++j) {
            const int row = wave * 16 + j * 8 + srow;
            // K tile row = key, 128 B
            gll16((const char*)kws + (kvbase + (size_t)(kk0 + row) * 64) * 2 + scol,
                  (char*)&Klds[buf][0][0] + row * 128 + scol);
            // V^T tile row = d, strided source rows (2048 elems apart)
            gll16((const char*)vtws + (((size_t)bh * 64 + row) * NSEQ + kk0) * 2 + scol,
                  (char*)&Vt[buf][0][0] + row * 128 + scol);
        }
    };

    float apf[4][4]; int mpf[4];
    auto pref = [&](int kk0) {
        #pragma unroll
        for (int nt = 0; nt < 4; ++nt) {
            const int key = kk0 + nt * 16 + lrow;
            mpf[nt] = mask_b[key];
            #pragma unroll
            for (int r = 0; r < 4; ++r)
                apf[nt][r] = alibi_w[(size_t)r * NSEQ + key];
        }
    };

    float mrow[4], lsum[4];
    f32x4 acc[4];
    #pragma unroll
    for (int r = 0; r < 4; ++r) { mrow[r] = -1e30f; lsum[r] = 0.f; }
    #pragma unroll
    for (int i = 0; i < 4; ++i) acc[i] = (f32x4){0.f, 0.f, 0.f, 0.f};

    stage(0, 0);
    pref(0);

    for (int it = 0; it < 32; ++it) {
        const int cur = it & 1;
        __syncthreads();                       // drains vmcnt: buf cur staged, prev reads done
        if (it < 31) stage((it + 1) * 64, cur ^ 1);

        float acur[4][4]; int mcur[4];
        #pragma unroll
        for (int nt = 0; nt < 4; ++nt) {
            mcur[nt] = mpf[nt];
            #pragma unroll
            for (int r = 0; r < 4; ++r) acur[nt][r] = apf[nt][r];
        }
        if (it < 31) pref((it + 1) * 64);      // overlaps with this tile's compute

        // ---- S = (q*scale) K^T : 4 n-frags x K=64 ----
        f32x4 s[4];
        #pragma unroll
        for (int nt = 0; nt < 4; ++nt) {
            bf16x8 kf0 = *(const bf16x8*)&Klds[cur][nt * 16 + lrow][quad * 8];
            bf16x8 kf1 = *(const bf16x8*)&Klds[cur][nt * 16 + lrow][32 + quad * 8];
            s[nt] = (f32x4){0.f, 0.f, 0.f, 0.f};
            s[nt] = __builtin_amdgcn_mfma_f32_16x16x32_bf16(qf0, kf0, s[nt], 0, 0, 0);
            s[nt] = __builtin_amdgcn_mfma_f32_16x16x32_bf16(qf1, kf1, s[nt], 0, 0, 0);
        }

        // ---- alibi + mask + online softmax; P -> LDS (bf16) ----
        #pragma unroll
        for (int r = 0; r < 4; ++r) {
            float vv[4];
            #pragma unroll
            for (int nt = 0; nt < 4; ++nt)
                vv[nt] = mcur[nt] ? -1e30f : (s[nt][r] + acur[nt][r]);
            float mx = fmaxf(fmaxf(vv[0], vv[1]), fmaxf(vv[2], vv[3]));
            mx = fmaxf(mx, __shfl_xor(mx, 1, 64));
            mx = fmaxf(mx, __shfl_xor(mx, 2, 64));
            mx = fmaxf(mx, __shfl_xor(mx, 4, 64));
            mx = fmaxf(mx, __shfl_xor(mx, 8, 64));
            const float mn = fmaxf(mrow[r], mx);
            const float alpha = __expf(mrow[r] - mn);
            mrow[r] = mn;
            float p[4], ps = 0.f;
            #pragma unroll
            for (int nt = 0; nt < 4; ++nt) { p[nt] = __expf(vv[nt] - mn); ps += p[nt]; }
            ps += __shfl_xor(ps, 1, 64);
            ps += __shfl_xor(ps, 2, 64);
            ps += __shfl_xor(ps, 4, 64);
            ps += __shfl_xor(ps, 8, 64);
            lsum[r] = lsum[r] * alpha + ps;
            #pragma unroll
            for (int nt = 0; nt < 4; ++nt) acc[nt][r] *= alpha;
            #pragma unroll
            for (int nt = 0; nt < 4; ++nt)
                Plds[wave][quad * 4 + r][nt * 16 + lrow] = f2bf(p[nt]);
        }

        // ---- O += P V : P via per-wave LDS transpose (A-layout); Vt gives B-layout ----
        bf16x8 pf0 = *(const bf16x8*)&Plds[wave][lrow][quad * 8];
        bf16x8 pf1 = *(const bf16x8*)&Plds[wave][lrow][32 + quad * 8];
        #pragma unroll
        for (int nt = 0; nt < 4; ++nt) {
            bf16x8 vf0 = *(const bf16x8*)&Vt[cur][nt * 16 + lrow][quad * 8];
            bf16x8 vf1 = *(const bf16x8*)&Vt[cur][nt * 16 + lrow][32 + quad * 8];
            acc[nt] = __builtin_amdgcn_mfma_f32_16x16x32_bf16(pf0, vf0, acc[nt], 0, 0, 0);
            acc[nt] = __builtin_amdgcn_mfma_f32_16x16x32_bf16(pf1, vf1, acc[nt], 0, 0, 0);
        }
    }

    // ---- epilogue: normalize, write doubled-K (hi,lo) bf16 rows of ao2[4096][2048] ----
    #pragma unroll
    for (int r = 0; r < 4; ++r) {
        const float inv = 1.f / lsum[r];
        const int m = b * NSEQ + q0 + wave * 16 + quad * 4 + r;
        #pragma unroll
        for (int nt = 0; nt < 4; ++nt) {
            const float o = acc[nt][r] * inv;
            const unsigned short hh_ = f2bf(o);
            const unsigned short ll_ = f2bf(o - bf2f(hh_));
            const int col = h * 64 + nt * 16 + lrow;
            *(unsigned*)&ao2[(size_t)m * 2048 + col * 2] =
                (unsigned)hh_ | ((unsigned)ll_ << 16);
        }
    }
}

extern "C" void kernel_launch(void* const* d_in, const int* in_sizes, int n_in,
                              void* d_out, int out_size, void* d_ws, size_t ws_size,
                              hipStream_t stream) {
    const float* x      = (const float*)d_in[0];
    const int*   mask   = (const int*)d_in[1];
    const float* alibi  = (const float*)d_in[2];
    const float* qkv_w  = (const float*)d_in[3];
    const float* proj_w = (const float*)d_in[4];
    const float* proj_b = (const float*)d_in[5];
    float* out = (float*)d_out;

    char* w = (char*)d_ws;
    unsigned short* qws    = (unsigned short*)(w);                    //  8 MB [32][2048][64]
    unsigned short* kws    = (unsigned short*)(w + 8388608);          //  8 MB
    unsigned short* vtws   = (unsigned short*)(w + 16777216);         //  8 MB [32][64][2048]
    unsigned short* x2     = (unsigned short*)(w + 25165824);         // 16 MB [4096][2048]
    unsigned short* ao2    = x2;                                      // alias: x2 dead after K1
    unsigned short* qkvw2  = (unsigned short*)(w + 41943040);         // 12 MB [3072][2048]
    unsigned short* projw2 = (unsigned short*)(w + 54525952);         //  4 MB [1024][2048]

    conv2<<<4096, 256, 0, stream>>>(x, x2, 1048576, 0);
    conv2<<<3072, 256, 0, stream>>>(qkv_w, qkvw2, 786432, 1);
    conv2<<<1024, 256, 0, stream>>>(proj_w, projw2, 262144, 1);
    // K1: qkv projection M=4096 N=3072 K'=2048
    gemm2k<0, 128><<<dim3(24, 32), 256, 0, stream>>>(x2, qkvw2, qws, kws, vtws, nullptr, nullptr);
    // K2: attention
    attn_fused<<<dim3(32, 32), 256, 0, stream>>>(qws, kws, vtws, alibi, mask, ao2);
    // K3: output projection M=4096 N=1024 K'=2048 (+bias)
    gemm2k<1, 64><<<dim3(16, 32), 256, 0, stream>>>(ao2, projw2, nullptr, nullptr, nullptr, out, proj_b);
}